// Round 6
// baseline (382.509 us; speedup 1.0000x reference)
//
#include <hip/hip_runtime.h>
#include <stdint.h>

#define N_NODES 50000
#define N_EDGES 800000
#define NFEAT 512
#define NHID 128
#define NCLASS 40
#define NB 196  // ceil(50000/256)

typedef __attribute__((ext_vector_type(8))) __bf16 bf16x8;
typedef __attribute__((ext_vector_type(4))) float f32x4;

__device__ __forceinline__ uint16_t f2b(float f) {
  uint32_t x = __float_as_uint(f);
  uint32_t r = (x + 0x7fffu + ((x >> 16) & 1u)) >> 16;
  return (uint16_t)r;
}
__device__ __forceinline__ float b2f(uint16_t u) {
  return __uint_as_float(((uint32_t)u) << 16);
}

// ---------------- cast x (fp32 -> bf16), 8 elems/thread ----------------
__global__ void k_cast_x(const float* __restrict__ x, uint16_t* __restrict__ xb, int n8) {
  int i = blockIdx.x * blockDim.x + threadIdx.x;
  if (i >= n8) return;
  const float4* p = (const float4*)x + (size_t)i * 2;
  float4 a = p[0], b = p[1];
  union { uint16_t u[8]; uint4 v; } o;
  o.u[0] = f2b(a.x); o.u[1] = f2b(a.y); o.u[2] = f2b(a.z); o.u[3] = f2b(a.w);
  o.u[4] = f2b(b.x); o.u[5] = f2b(b.y); o.u[6] = f2b(b.z); o.u[7] = f2b(b.w);
  ((uint4*)xb)[i] = o.v;
}

// ---------------- weight prep ----------------
__global__ void k_prep_w1(const float* __restrict__ W1, const float* __restrict__ Wr1,
                          uint16_t* __restrict__ WT) {
  int idx = blockIdx.x * 256 + threadIdx.x;  // 256*512
  if (idx >= 256 * 512) return;
  int n = idx >> 9, k = idx & 511;
  float v = (n < 128) ? W1[(size_t)k * 128 + n] : Wr1[(size_t)k * 128 + (n - 128)];
  WT[idx] = f2b(v);
}

__global__ void k_prep_w2(const float* __restrict__ W2, const float* __restrict__ Wr2,
                          uint16_t* __restrict__ WT) {
  int idx = blockIdx.x * 256 + threadIdx.x;  // 128*256
  if (idx >= 128 * 256) return;
  int n = idx >> 8, k = idx & 255;
  float v = 0.f;
  if (n < 40) v = W2[(size_t)k * 40 + n];
  else if (n < 80) v = Wr2[(size_t)k * 40 + (n - 40)];
  WT[idx] = f2b(v);
}

// ---------------- CSR build ----------------
__global__ void k_hist(const int* __restrict__ dst, int* __restrict__ counts) {
  int e = blockIdx.x * 256 + threadIdx.x;
  if (e < N_EDGES) atomicAdd(&counts[dst[e]], 1);
}

__global__ void k_blocksum(const int* __restrict__ counts, int* __restrict__ blocksums) {
  __shared__ int red[256];
  int t = threadIdx.x, idx = blockIdx.x * 256 + t;
  red[t] = (idx < N_NODES) ? counts[idx] : 0;
  __syncthreads();
  for (int o = 128; o; o >>= 1) {
    if (t < o) red[t] += red[t + o];
    __syncthreads();
  }
  if (t == 0) blocksums[blockIdx.x] = red[0];
}

__global__ void k_scan2(const int* __restrict__ counts, const int* __restrict__ blocksums,
                        int* __restrict__ offs) {
  __shared__ int red[256];
  __shared__ int sc[256];
  int b = blockIdx.x, t = threadIdx.x;
  red[t] = (t < b && t < NB) ? blocksums[t] : 0;
  __syncthreads();
  for (int o = 128; o; o >>= 1) {
    if (t < o) red[t] += red[t + o];
    __syncthreads();
  }
  int prefix = red[0];
  int idx = b * 256 + t;
  int c = (idx < N_NODES) ? counts[idx] : 0;
  sc[t] = c;
  __syncthreads();
  for (int o = 1; o < 256; o <<= 1) {
    int v = (t >= o) ? sc[t - o] : 0;
    __syncthreads();
    sc[t] += v;
    __syncthreads();
  }
  if (idx <= N_NODES) offs[idx] = prefix + sc[t] - c;
}

__global__ void k_scatter(const int* __restrict__ src, const int* __restrict__ dst,
                          const float* __restrict__ val, const int* __restrict__ offs,
                          int* __restrict__ cursor, int2* __restrict__ es) {
  int e = blockIdx.x * 256 + threadIdx.x;
  if (e >= N_EDGES) return;
  int d = dst[e];
  int pos = offs[d] + atomicAdd(&cursor[d], 1);
  es[pos] = make_int2(src[e], __float_as_int(val[e]));
}

// ---------------- GEMM1: xb(bf16) @ WT1^T, 128x128 tile, m97 structure (R3-proven) ----------------
__global__ __launch_bounds__(256, 2) void k_gemm1(
    const uint16_t* __restrict__ A, const uint16_t* __restrict__ BT, int M,
    uint16_t* __restrict__ S1b, uint16_t* __restrict__ h, const float* __restrict__ br1) {
  __shared__ uint16_t Al[128 * 64];
  __shared__ uint16_t Bl[128 * 64];
  const int tid = threadIdx.x;
  const int w = tid >> 6, lane = tid & 63;
  const int wm = w >> 1, wn = w & 1;
  const int m0 = blockIdx.x * 128;
  const int n0 = blockIdx.y * 128;
  const int K = NFEAT;

  f32x4 acc[4][4];
#pragma unroll
  for (int t = 0; t < 4; t++)
#pragma unroll
    for (int u = 0; u < 4; u++) acc[t][u] = (f32x4)0.f;

  const int lrow = lane >> 3;
  const int lcol = lane & 7;

  for (int kb = 0; kb < K / 64; ++kb) {
    __syncthreads();
    const int k0 = kb * 64;
#pragma unroll
    for (int i = 0; i < 4; i++) {
      int rr = (w * 4 + i) * 8 + lrow;
      int ra = m0 + rr;
      if (ra >= M) ra = M - 1;  // clamp tail rows (stores are guarded)
      const uint16_t* gA = A + (size_t)ra * K + k0 + lcol * 8;
      __builtin_amdgcn_global_load_lds(
          (const __attribute__((address_space(1))) void*)gA,
          (__attribute__((address_space(3))) void*)&Al[(w * 4 + i) * 512], 16, 0, 0);
      int rb = n0 + rr;
      const uint16_t* gB = BT + (size_t)rb * K + k0 + lcol * 8;
      __builtin_amdgcn_global_load_lds(
          (const __attribute__((address_space(1))) void*)gB,
          (__attribute__((address_space(3))) void*)&Bl[(w * 4 + i) * 512], 16, 0, 0);
    }
    __syncthreads();
#pragma unroll
    for (int s = 0; s < 2; s++) {
      bf16x8 av[4], bv[4];
#pragma unroll
      for (int t = 0; t < 4; t++)
        av[t] = *(const bf16x8*)&Al[(wm * 64 + t * 16 + (lane & 15)) * 64 + s * 32 + (lane >> 4) * 8];
#pragma unroll
      for (int u = 0; u < 4; u++)
        bv[u] = *(const bf16x8*)&Bl[(wn * 64 + u * 16 + (lane & 15)) * 64 + s * 32 + (lane >> 4) * 8];
#pragma unroll
      for (int t = 0; t < 4; t++)
#pragma unroll
        for (int u = 0; u < 4; u++)
          acc[t][u] = __builtin_amdgcn_mfma_f32_16x16x32_bf16(av[t], bv[u], acc[t][u], 0, 0, 0);
    }
  }

  const int cl = lane & 15, rq = lane >> 4;
#pragma unroll
  for (int t = 0; t < 4; t++) {
#pragma unroll
    for (int u = 0; u < 4; u++) {
#pragma unroll
      for (int r = 0; r < 4; r++) {
        int m = m0 + wm * 64 + t * 16 + rq * 4 + r;
        int n = n0 + wn * 64 + u * 16 + cl;
        if (m >= M) continue;
        float v = acc[t][u][r];
        if (n < 128)
          S1b[(size_t)m * 128 + n] = f2b(v);  // x@W1 (b1 added post-spmm)
        else
          h[(size_t)m * 256 + n] = f2b(v + br1[n - 128]);  // h right = x@Wr1+br1
      }
    }
  }
}

// ---------------- GEMM2: h(bf16) @ WT2^T, 128x128 tile, padded epilogue (R4-proven) ----------------
__global__ __launch_bounds__(256, 2) void k_gemm2(
    const uint16_t* __restrict__ A, const uint16_t* __restrict__ BT, int M,
    uint16_t* __restrict__ S2b, float* __restrict__ oacc,
    const float* __restrict__ b2, const float* __restrict__ br2) {
  __shared__ uint16_t Al[128 * 64];
  __shared__ uint16_t Bl[128 * 64];
  const int tid = threadIdx.x;
  const int w = tid >> 6, lane = tid & 63;
  const int wm = w >> 1, wn = w & 1;
  const int m0 = blockIdx.x * 128;
  const int K = 256;

  f32x4 acc[4][4];
#pragma unroll
  for (int t = 0; t < 4; t++)
#pragma unroll
    for (int u = 0; u < 4; u++) acc[t][u] = (f32x4)0.f;

  const int lrow = lane >> 3;
  const int lcol = lane & 7;

  for (int kb = 0; kb < K / 64; ++kb) {
    __syncthreads();
    const int k0 = kb * 64;
#pragma unroll
    for (int i = 0; i < 4; i++) {
      int rr = (w * 4 + i) * 8 + lrow;
      int ra = m0 + rr;
      if (ra >= M) ra = M - 1;
      const uint16_t* gA = A + (size_t)ra * K + k0 + lcol * 8;
      __builtin_amdgcn_global_load_lds(
          (const __attribute__((address_space(1))) void*)gA,
          (__attribute__((address_space(3))) void*)&Al[(w * 4 + i) * 512], 16, 0, 0);
      const uint16_t* gB = BT + (size_t)rr * K + k0 + lcol * 8;
      __builtin_amdgcn_global_load_lds(
          (const __attribute__((address_space(1))) void*)gB,
          (__attribute__((address_space(3))) void*)&Bl[(w * 4 + i) * 512], 16, 0, 0);
    }
    __syncthreads();
#pragma unroll
    for (int s = 0; s < 2; s++) {
      bf16x8 av[4], bv[4];
#pragma unroll
      for (int t = 0; t < 4; t++)
        av[t] = *(const bf16x8*)&Al[(wm * 64 + t * 16 + (lane & 15)) * 64 + s * 32 + (lane >> 4) * 8];
#pragma unroll
      for (int u = 0; u < 4; u++)
        bv[u] = *(const bf16x8*)&Bl[(wn * 64 + u * 16 + (lane & 15)) * 64 + s * 32 + (lane >> 4) * 8];
#pragma unroll
      for (int t = 0; t < 4; t++)
#pragma unroll
        for (int u = 0; u < 4; u++)
          acc[t][u] = __builtin_amdgcn_mfma_f32_16x16x32_bf16(av[t], bv[u], acc[t][u], 0, 0, 0);
    }
  }

  const int cl = lane & 15, rq = lane >> 4;
#pragma unroll
  for (int t = 0; t < 4; t++) {
#pragma unroll
    for (int u = 0; u < 4; u++) {
#pragma unroll
      for (int r = 0; r < 4; r++) {
        int m = m0 + wm * 64 + t * 16 + rq * 4 + r;
        int n = wn * 64 + u * 16 + cl;
        if (m >= M) continue;
        float v = acc[t][u][r];
        if (n < 40) S2b[(size_t)m * 64 + n] = f2b(v);
        else if (n < 64) S2b[(size_t)m * 64 + n] = 0;
        if (n >= 40 && n < 80) oacc[(size_t)m * 64 + (n - 40)] = v + b2[n - 40] + br2[n - 40];
        else if (n >= 80 && n < 104) oacc[(size_t)m * 64 + (n - 40)] = 0.f;
      }
    }
  }
}

// ---------------- SpMM1 via CSR: wave/node, 4 edges/iter, dwordx4 gathers (R4-proven) ----------------
__global__ void k_spmm1_csr(const int* __restrict__ offs, const int2* __restrict__ es,
                            const uint16_t* __restrict__ S1b, const float* __restrict__ b1,
                            uint16_t* __restrict__ h) {
  int node = blockIdx.x * 4 + (threadIdx.x >> 6);
  if (node >= N_NODES) return;
  int lane = threadIdx.x & 63;
  int eg = lane >> 4;  // 0..3 edge slot
  int fg = lane & 15;  // 0..15 feat group (8 feats)
  int beg = offs[node], end = offs[node + 1];
  float a[8];
#pragma unroll
  for (int j = 0; j < 8; j++) a[j] = 0.f;
  for (int p = beg; p < end; p += 4) {
    int pe = p + eg;
    bool ok = pe < end;
    int2 ev = es[ok ? pe : beg];
    float v = ok ? __int_as_float(ev.y) : 0.f;
    uint4 g = *(const uint4*)(S1b + (size_t)ev.x * 128 + fg * 8);
    a[0] += v * b2f((uint16_t)g.x); a[1] += v * b2f((uint16_t)(g.x >> 16));
    a[2] += v * b2f((uint16_t)g.y); a[3] += v * b2f((uint16_t)(g.y >> 16));
    a[4] += v * b2f((uint16_t)g.z); a[5] += v * b2f((uint16_t)(g.z >> 16));
    a[6] += v * b2f((uint16_t)g.w); a[7] += v * b2f((uint16_t)(g.w >> 16));
  }
#pragma unroll
  for (int j = 0; j < 8; j++) {
    a[j] += __shfl_xor(a[j], 16, 64);
    a[j] += __shfl_xor(a[j], 32, 64);
  }
  if (eg == 0) {
    const float4* bp = (const float4*)(b1 + fg * 8);
    float4 ba = bp[0], bb = bp[1];
    float r0 = a[0] + ba.x, r1 = a[1] + ba.y, r2 = a[2] + ba.z, r3 = a[3] + ba.w;
    float r4 = a[4] + bb.x, r5 = a[5] + bb.y, r6 = a[6] + bb.z, r7 = a[7] + bb.w;
    union { uint16_t u[8]; uint4 v; } o;
    o.u[0] = f2b(r0 > 0.f ? r0 : 0.f); o.u[1] = f2b(r1 > 0.f ? r1 : 0.f);
    o.u[2] = f2b(r2 > 0.f ? r2 : 0.f); o.u[3] = f2b(r3 > 0.f ? r3 : 0.f);
    o.u[4] = f2b(r4 > 0.f ? r4 : 0.f); o.u[5] = f2b(r5 > 0.f ? r5 : 0.f);
    o.u[6] = f2b(r6 > 0.f ? r6 : 0.f); o.u[7] = f2b(r7 > 0.f ? r7 : 0.f);
    *(uint4*)(h + (size_t)node * 256 + fg * 8) = o.v;
  }
}

// ---------------- SpMM2 via CSR + log_softmax: wave/node, 8 edges/iter (R4-proven) ----------------
__global__ void k_spmm2_lsm(const int* __restrict__ offs, const int2* __restrict__ es,
                            const uint16_t* __restrict__ S2b, const float* __restrict__ oacc,
                            float* __restrict__ out) {
  int node = blockIdx.x * 4 + (threadIdx.x >> 6);
  if (node >= N_NODES) return;
  int lane = threadIdx.x & 63;
  int eg = lane >> 3;  // 0..7 edge slot
  int fg = lane & 7;   // 0..7 feat group (8 feats of 64-padded row)
  int beg = offs[node], end = offs[node + 1];
  float a[8];
#pragma unroll
  for (int j = 0; j < 8; j++) a[j] = 0.f;
  for (int p = beg; p < end; p += 8) {
    int pe = p + eg;
    bool ok = pe < end;
    int2 ev = es[ok ? pe : beg];
    float v = ok ? __int_as_float(ev.y) : 0.f;
    uint4 g = *(const uint4*)(S2b + (size_t)ev.x * 64 + fg * 8);
    a[0] += v * b2f((uint16_t)g.x); a[1] += v * b2f((uint16_t)(g.x >> 16));
    a[2] += v * b2f((uint16_t)g.y); a[3] += v * b2f((uint16_t)(g.y >> 16));
    a[4] += v * b2f((uint16_t)g.z); a[5] += v * b2f((uint16_t)(g.z >> 16));
    a[6] += v * b2f((uint16_t)g.w); a[7] += v * b2f((uint16_t)(g.w >> 16));
  }
#pragma unroll
  for (int j = 0; j < 8; j++) {
    a[j] += __shfl_xor(a[j], 8, 64);
    a[j] += __shfl_xor(a[j], 16, 64);
    a[j] += __shfl_xor(a[j], 32, 64);
  }
  const float4* op = (const float4*)(oacc + (size_t)node * 64 + fg * 8);
  float4 o0 = op[0], o1 = op[1];
  float v0 = a[0] + o0.x, v1 = a[1] + o0.y, v2 = a[2] + o0.z, v3 = a[3] + o0.w;
  float v4 = a[4] + o1.x, v5 = a[5] + o1.y, v6 = a[6] + o1.z, v7 = a[7] + o1.w;
  bool valid = fg < 5;  // feats 0..39
  float m01 = v0 > v1 ? v0 : v1, m23 = v2 > v3 ? v2 : v3;
  float m45 = v4 > v5 ? v4 : v5, m67 = v6 > v7 ? v6 : v7;
  float ml = m01 > m23 ? m01 : m23;
  float mh = m45 > m67 ? m45 : m67;
  float mv = ml > mh ? ml : mh;
  mv = valid ? mv : -1e30f;
#pragma unroll
  for (int o = 1; o <= 4; o <<= 1) {
    float t = __shfl_xor(mv, o, 64);
    mv = mv > t ? mv : t;
  }
  float se = 0.f;
  if (valid)
    se = __expf(v0 - mv) + __expf(v1 - mv) + __expf(v2 - mv) + __expf(v3 - mv) +
         __expf(v4 - mv) + __expf(v5 - mv) + __expf(v6 - mv) + __expf(v7 - mv);
#pragma unroll
  for (int o = 1; o <= 4; o <<= 1) se += __shfl_xor(se, o, 64);
  if (eg == 0 && valid) {
    float ls = mv + __logf(se);
    float4 r0 = make_float4(v0 - ls, v1 - ls, v2 - ls, v3 - ls);
    float4 r1 = make_float4(v4 - ls, v5 - ls, v6 - ls, v7 - ls);
    float4* wp = (float4*)(out + (size_t)node * 40 + fg * 8);
    wp[0] = r0;
    wp[1] = r1;
  }
}

extern "C" void kernel_launch(void* const* d_in, const int* in_sizes, int n_in,
                              void* d_out, int out_size, void* d_ws, size_t ws_size,
                              hipStream_t stream) {
  const float* x = (const float*)d_in[0];
  const int* esrc = (const int*)d_in[1];
  const int* edst = (const int*)d_in[2];
  const float* eval = (const float*)d_in[3];
  const float* W1 = (const float*)d_in[4];
  const float* b1 = (const float*)d_in[5];
  const float* Wr1 = (const float*)d_in[6];
  const float* br1 = (const float*)d_in[7];
  const float* W2 = (const float*)d_in[8];
  const float* b2 = (const float*)d_in[9];
  const float* Wr2 = (const float*)d_in[10];
  const float* br2 = (const float*)d_in[11];
  float* out = (float*)d_out;

  char* ws = (char*)d_ws;
  uint16_t* xb   = (uint16_t*)(ws);              // 51,200,000
  uint16_t* S1b  = (uint16_t*)(ws + 51200000);   // 12,800,000
  uint16_t* h    = (uint16_t*)(ws + 64000000);   // 25,600,000
  uint16_t* WT1  = (uint16_t*)(ws + 89600000);   //    262,144
  uint16_t* WT2  = (uint16_t*)(ws + 89862144);   //     65,536
  uint16_t* S2b  = (uint16_t*)(ws + 89927680);   //  6,400,000 (64-padded)
  float*    oacc = (float*)(ws + 96327680);      // 12,800,000 (64-padded)
  int*      counts = (int*)(ws + 109127680);     //    200,000
  int*      cursor = (int*)(ws + 109327680);     //    200,000
  int*      offs   = (int*)(ws + 109527680);     //    200,016 (padded for alignment)
  int2*     es     = (int2*)(ws + 109727696);    //  6,400,000
  int*      blocksums = (int*)(ws + 116127696);  //        784  (total ~116.13 MB)

  hipMemsetAsync(counts, 0, 400000, stream);  // counts + cursor (adjacent)

  k_cast_x<<<(3200000 + 255) / 256, 256, 0, stream>>>(x, xb, 3200000);
  k_prep_w1<<<(256 * 512) / 256, 256, 0, stream>>>(W1, Wr1, WT1);
  k_prep_w2<<<(128 * 256) / 256, 256, 0, stream>>>(W2, Wr2, WT2);

  k_hist<<<(N_EDGES + 255) / 256, 256, 0, stream>>>(edst, counts);
  k_blocksum<<<NB, 256, 0, stream>>>(counts, blocksums);
  k_scan2<<<NB, 256, 0, stream>>>(counts, blocksums, offs);
  k_scatter<<<(N_EDGES + 255) / 256, 256, 0, stream>>>(esrc, edst, eval, offs, cursor, es);

  dim3 g1(391, 2);
  k_gemm1<<<g1, 256, 0, stream>>>(xb, WT1, N_NODES, S1b, h, br1);

  k_spmm1_csr<<<(N_NODES + 3) / 4, 256, 0, stream>>>(offs, es, S1b, b1, h);

  k_gemm2<<<391, 256, 0, stream>>>(h, WT2, N_NODES, S2b, oacc, b2, br2);

  k_spmm2_lsm<<<(N_NODES + 3) / 4, 256, 0, stream>>>(offs, es, S2b, oacc, out);
}

// Round 7
// 366.680 us; speedup vs baseline: 1.0432x; 1.0432x over previous
//
#include <hip/hip_runtime.h>
#include <stdint.h>

#define N_NODES 50000
#define N_EDGES 800000
#define NFEAT 512
#define NHID 128
#define NCLASS 40
#define NB 196  // ceil(50000/256)

typedef __attribute__((ext_vector_type(8))) __bf16 bf16x8;
typedef __attribute__((ext_vector_type(4))) float f32x4;
typedef _Float16 h2 __attribute__((ext_vector_type(2)));

__device__ __forceinline__ uint16_t f2b(float f) {
  uint32_t x = __float_as_uint(f);
  uint32_t r = (x + 0x7fffu + ((x >> 16) & 1u)) >> 16;
  return (uint16_t)r;
}

// ---------------- merged prologue: cast x, prep WT1, prep WT2, hist(dst) ----------------
// blocks [0,12500): cast | [12500,13012): WT1 | [13012,13140): WT2 | [13140,16265): hist
__global__ void k_pre(const float* __restrict__ x, uint16_t* __restrict__ xb,
                      const float* __restrict__ W1, const float* __restrict__ Wr1,
                      uint16_t* __restrict__ WT1,
                      const float* __restrict__ W2, const float* __restrict__ Wr2,
                      uint16_t* __restrict__ WT2,
                      const int* __restrict__ dst, int* __restrict__ counts) {
  int b = blockIdx.x, tid = threadIdx.x;
  if (b < 12500) {
    int i = b * 256 + tid;  // 3,200,000 uint4 groups
    const float4* p = (const float4*)x + (size_t)i * 2;
    float4 a = p[0], c = p[1];
    union { uint16_t u[8]; uint4 v; } o;
    o.u[0] = f2b(a.x); o.u[1] = f2b(a.y); o.u[2] = f2b(a.z); o.u[3] = f2b(a.w);
    o.u[4] = f2b(c.x); o.u[5] = f2b(c.y); o.u[6] = f2b(c.z); o.u[7] = f2b(c.w);
    ((uint4*)xb)[i] = o.v;
  } else if (b < 13012) {
    int idx = (b - 12500) * 256 + tid;  // 131072
    int n = idx >> 9, k = idx & 511;
    float v = (n < 128) ? W1[(size_t)k * 128 + n] : Wr1[(size_t)k * 128 + (n - 128)];
    WT1[idx] = f2b(v);
  } else if (b < 13140) {
    int idx = (b - 13012) * 256 + tid;  // 32768
    int n = idx >> 8, k = idx & 255;
    float v = 0.f;
    if (n < 40) v = W2[(size_t)k * 40 + n];
    else if (n < 80) v = Wr2[(size_t)k * 40 + (n - 40)];
    WT2[idx] = f2b(v);
  } else {
    int e = (b - 13140) * 256 + tid;  // 800000 exactly
    atomicAdd(&counts[dst[e]], 1);
  }
}

// ---------------- CSR build ----------------
__global__ void k_blocksum(const int* __restrict__ counts, int* __restrict__ blocksums) {
  __shared__ int red[256];
  int t = threadIdx.x, idx = blockIdx.x * 256 + t;
  red[t] = (idx < N_NODES) ? counts[idx] : 0;
  __syncthreads();
  for (int o = 128; o; o >>= 1) {
    if (t < o) red[t] += red[t + o];
    __syncthreads();
  }
  if (t == 0) blocksums[blockIdx.x] = red[0];
}

__global__ void k_scan2(const int* __restrict__ counts, const int* __restrict__ blocksums,
                        int* __restrict__ offs) {
  __shared__ int red[256];
  __shared__ int sc[256];
  int b = blockIdx.x, t = threadIdx.x;
  red[t] = (t < b && t < NB) ? blocksums[t] : 0;
  __syncthreads();
  for (int o = 128; o; o >>= 1) {
    if (t < o) red[t] += red[t + o];
    __syncthreads();
  }
  int prefix = red[0];
  int idx = b * 256 + t;
  int c = (idx < N_NODES) ? counts[idx] : 0;
  sc[t] = c;
  __syncthreads();
  for (int o = 1; o < 256; o <<= 1) {
    int v = (t >= o) ? sc[t - o] : 0;
    __syncthreads();
    sc[t] += v;
    __syncthreads();
  }
  if (idx <= N_NODES) offs[idx] = prefix + sc[t] - c;
}

__global__ void k_scatter(const int* __restrict__ src, const int* __restrict__ dst,
                          const float* __restrict__ val, const int* __restrict__ offs,
                          int* __restrict__ cursor, int2* __restrict__ es) {
  int e = blockIdx.x * 256 + threadIdx.x;
  if (e >= N_EDGES) return;
  int d = dst[e];
  int pos = offs[d] + atomicAdd(&cursor[d], 1);
  es[pos] = make_int2(src[e], __float_as_int(val[e]));
}

// ---------------- GEMM1: xb(bf16) @ WT1^T, 128x128 tile, m97 structure ----------------
// S1 now stored as f16 (consumed by packed-f16 spmm1); h right half stays bf16.
__global__ __launch_bounds__(256, 2) void k_gemm1(
    const uint16_t* __restrict__ A, const uint16_t* __restrict__ BT, int M,
    _Float16* __restrict__ S1h, uint16_t* __restrict__ h, const float* __restrict__ br1) {
  __shared__ uint16_t Al[128 * 64];
  __shared__ uint16_t Bl[128 * 64];
  const int tid = threadIdx.x;
  const int w = tid >> 6, lane = tid & 63;
  const int wm = w >> 1, wn = w & 1;
  const int m0 = blockIdx.x * 128;
  const int n0 = blockIdx.y * 128;
  const int K = NFEAT;

  f32x4 acc[4][4];
#pragma unroll
  for (int t = 0; t < 4; t++)
#pragma unroll
    for (int u = 0; u < 4; u++) acc[t][u] = (f32x4)0.f;

  const int lrow = lane >> 3;
  const int lcol = lane & 7;

  for (int kb = 0; kb < K / 64; ++kb) {
    __syncthreads();
    const int k0 = kb * 64;
#pragma unroll
    for (int i = 0; i < 4; i++) {
      int rr = (w * 4 + i) * 8 + lrow;
      int ra = m0 + rr;
      if (ra >= M) ra = M - 1;  // clamp tail rows (stores are guarded)
      const uint16_t* gA = A + (size_t)ra * K + k0 + lcol * 8;
      __builtin_amdgcn_global_load_lds(
          (const __attribute__((address_space(1))) void*)gA,
          (__attribute__((address_space(3))) void*)&Al[(w * 4 + i) * 512], 16, 0, 0);
      int rb = n0 + rr;
      const uint16_t* gB = BT + (size_t)rb * K + k0 + lcol * 8;
      __builtin_amdgcn_global_load_lds(
          (const __attribute__((address_space(1))) void*)gB,
          (__attribute__((address_space(3))) void*)&Bl[(w * 4 + i) * 512], 16, 0, 0);
    }
    __syncthreads();
#pragma unroll
    for (int s = 0; s < 2; s++) {
      bf16x8 av[4], bv[4];
#pragma unroll
      for (int t = 0; t < 4; t++)
        av[t] = *(const bf16x8*)&Al[(wm * 64 + t * 16 + (lane & 15)) * 64 + s * 32 + (lane >> 4) * 8];
#pragma unroll
      for (int u = 0; u < 4; u++)
        bv[u] = *(const bf16x8*)&Bl[(wn * 64 + u * 16 + (lane & 15)) * 64 + s * 32 + (lane >> 4) * 8];
#pragma unroll
      for (int t = 0; t < 4; t++)
#pragma unroll
        for (int u = 0; u < 4; u++)
          acc[t][u] = __builtin_amdgcn_mfma_f32_16x16x32_bf16(av[t], bv[u], acc[t][u], 0, 0, 0);
    }
  }

  const int cl = lane & 15, rq = lane >> 4;
#pragma unroll
  for (int t = 0; t < 4; t++) {
#pragma unroll
    for (int u = 0; u < 4; u++) {
#pragma unroll
      for (int r = 0; r < 4; r++) {
        int m = m0 + wm * 64 + t * 16 + rq * 4 + r;
        int n = n0 + wn * 64 + u * 16 + cl;
        if (m >= M) continue;
        float v = acc[t][u][r];
        if (n < 128)
          S1h[(size_t)m * 128 + n] = (_Float16)v;  // x@W1 (b1 added post-spmm)
        else
          h[(size_t)m * 256 + n] = f2b(v + br1[n - 128]);  // h right = x@Wr1+br1
      }
    }
  }
}

// ---------------- GEMM2: h(bf16) @ WT2^T, 128x128 tile, f16 S2 + padded epilogue ----------------
__global__ __launch_bounds__(256, 2) void k_gemm2(
    const uint16_t* __restrict__ A, const uint16_t* __restrict__ BT, int M,
    _Float16* __restrict__ S2h, float* __restrict__ oacc,
    const float* __restrict__ b2, const float* __restrict__ br2) {
  __shared__ uint16_t Al[128 * 64];
  __shared__ uint16_t Bl[128 * 64];
  const int tid = threadIdx.x;
  const int w = tid >> 6, lane = tid & 63;
  const int wm = w >> 1, wn = w & 1;
  const int m0 = blockIdx.x * 128;
  const int K = 256;

  f32x4 acc[4][4];
#pragma unroll
  for (int t = 0; t < 4; t++)
#pragma unroll
    for (int u = 0; u < 4; u++) acc[t][u] = (f32x4)0.f;

  const int lrow = lane >> 3;
  const int lcol = lane & 7;

  for (int kb = 0; kb < K / 64; ++kb) {
    __syncthreads();
    const int k0 = kb * 64;
#pragma unroll
    for (int i = 0; i < 4; i++) {
      int rr = (w * 4 + i) * 8 + lrow;
      int ra = m0 + rr;
      if (ra >= M) ra = M - 1;
      const uint16_t* gA = A + (size_t)ra * K + k0 + lcol * 8;
      __builtin_amdgcn_global_load_lds(
          (const __attribute__((address_space(1))) void*)gA,
          (__attribute__((address_space(3))) void*)&Al[(w * 4 + i) * 512], 16, 0, 0);
      const uint16_t* gB = BT + (size_t)rr * K + k0 + lcol * 8;
      __builtin_amdgcn_global_load_lds(
          (const __attribute__((address_space(1))) void*)gB,
          (__attribute__((address_space(3))) void*)&Bl[(w * 4 + i) * 512], 16, 0, 0);
    }
    __syncthreads();
#pragma unroll
    for (int s = 0; s < 2; s++) {
      bf16x8 av[4], bv[4];
#pragma unroll
      for (int t = 0; t < 4; t++)
        av[t] = *(const bf16x8*)&Al[(wm * 64 + t * 16 + (lane & 15)) * 64 + s * 32 + (lane >> 4) * 8];
#pragma unroll
      for (int u = 0; u < 4; u++)
        bv[u] = *(const bf16x8*)&Bl[(wn * 64 + u * 16 + (lane & 15)) * 64 + s * 32 + (lane >> 4) * 8];
#pragma unroll
      for (int t = 0; t < 4; t++)
#pragma unroll
        for (int u = 0; u < 4; u++)
          acc[t][u] = __builtin_amdgcn_mfma_f32_16x16x32_bf16(av[t], bv[u], acc[t][u], 0, 0, 0);
    }
  }

  const int cl = lane & 15, rq = lane >> 4;
#pragma unroll
  for (int t = 0; t < 4; t++) {
#pragma unroll
    for (int u = 0; u < 4; u++) {
#pragma unroll
      for (int r = 0; r < 4; r++) {
        int m = m0 + wm * 64 + t * 16 + rq * 4 + r;
        int n = wn * 64 + u * 16 + cl;
        if (m >= M) continue;
        float v = acc[t][u][r];
        if (n < 40) S2h[(size_t)m * 64 + n] = (_Float16)v;
        else if (n < 64) S2h[(size_t)m * 64 + n] = (_Float16)0.f;
        if (n >= 40 && n < 80) oacc[(size_t)m * 64 + (n - 40)] = v + b2[n - 40] + br2[n - 40];
        else if (n >= 80 && n < 104) oacc[(size_t)m * 64 + (n - 40)] = 0.f;
      }
    }
  }
}

// ---------------- SpMM1 via CSR: wave/node, 4 edges/iter, f16 packed FMA ----------------
__global__ void k_spmm1_csr(const int* __restrict__ offs, const int2* __restrict__ es,
                            const _Float16* __restrict__ S1h, const float* __restrict__ b1,
                            uint16_t* __restrict__ h) {
  int node = blockIdx.x * 4 + (threadIdx.x >> 6);
  if (node >= N_NODES) return;
  int lane = threadIdx.x & 63;
  int eg = lane >> 4;  // 0..3 edge slot
  int fg = lane & 15;  // 0..15 feat group (8 feats)
  int beg = offs[node], end = offs[node + 1];
  h2 acc[4];
#pragma unroll
  for (int j = 0; j < 4; j++) acc[j] = (h2)(_Float16)0.f;
  for (int p = beg; p < end; p += 4) {
    int pe = p + eg;
    bool ok = pe < end;
    int2 ev = es[ok ? pe : beg];
    float v = ok ? __int_as_float(ev.y) : 0.f;
    _Float16 vh = (_Float16)v;
    h2 vv = {vh, vh};
    uint4 g = *(const uint4*)(S1h + (size_t)ev.x * 128 + fg * 8);
    h2* hp = (h2*)&g;
#pragma unroll
    for (int j = 0; j < 4; j++) acc[j] = vv * hp[j] + acc[j];
  }
  // packed cross-lane reduce over eg (xor 16, 32)
#pragma unroll
  for (int j = 0; j < 4; j++) {
    int b16 = __shfl_xor(__builtin_bit_cast(int, acc[j]), 16, 64);
    acc[j] = acc[j] + __builtin_bit_cast(h2, b16);
    int b32 = __shfl_xor(__builtin_bit_cast(int, acc[j]), 32, 64);
    acc[j] = acc[j] + __builtin_bit_cast(h2, b32);
  }
  if (eg == 0) {
    const float4* bp = (const float4*)(b1 + fg * 8);
    float4 ba = bp[0], bb = bp[1];
    float r0 = (float)acc[0][0] + ba.x, r1 = (float)acc[0][1] + ba.y;
    float r2 = (float)acc[1][0] + ba.z, r3 = (float)acc[1][1] + ba.w;
    float r4 = (float)acc[2][0] + bb.x, r5 = (float)acc[2][1] + bb.y;
    float r6 = (float)acc[3][0] + bb.z, r7 = (float)acc[3][1] + bb.w;
    union { uint16_t u[8]; uint4 v; } o;
    o.u[0] = f2b(r0 > 0.f ? r0 : 0.f); o.u[1] = f2b(r1 > 0.f ? r1 : 0.f);
    o.u[2] = f2b(r2 > 0.f ? r2 : 0.f); o.u[3] = f2b(r3 > 0.f ? r3 : 0.f);
    o.u[4] = f2b(r4 > 0.f ? r4 : 0.f); o.u[5] = f2b(r5 > 0.f ? r5 : 0.f);
    o.u[6] = f2b(r6 > 0.f ? r6 : 0.f); o.u[7] = f2b(r7 > 0.f ? r7 : 0.f);
    *(uint4*)(h + (size_t)node * 256 + fg * 8) = o.v;
  }
}

// ---------------- SpMM2 via CSR + log_softmax: wave/node, 8 edges/iter, f16 packed ----------------
__global__ void k_spmm2_lsm(const int* __restrict__ offs, const int2* __restrict__ es,
                            const _Float16* __restrict__ S2h, const float* __restrict__ oacc,
                            float* __restrict__ out) {
  int node = blockIdx.x * 4 + (threadIdx.x >> 6);
  if (node >= N_NODES) return;
  int lane = threadIdx.x & 63;
  int eg = lane >> 3;  // 0..7 edge slot
  int fg = lane & 7;   // 0..7 feat group (8 feats of 64-padded row)
  int beg = offs[node], end = offs[node + 1];
  h2 acc[4];
#pragma unroll
  for (int j = 0; j < 4; j++) acc[j] = (h2)(_Float16)0.f;
  for (int p = beg; p < end; p += 8) {
    int pe = p + eg;
    bool ok = pe < end;
    int2 ev = es[ok ? pe : beg];
    float v = ok ? __int_as_float(ev.y) : 0.f;
    _Float16 vh = (_Float16)v;
    h2 vv = {vh, vh};
    uint4 g = *(const uint4*)(S2h + (size_t)ev.x * 64 + fg * 8);
    h2* hp = (h2*)&g;
#pragma unroll
    for (int j = 0; j < 4; j++) acc[j] = vv * hp[j] + acc[j];
  }
#pragma unroll
  for (int j = 0; j < 4; j++) {
    int b8 = __shfl_xor(__builtin_bit_cast(int, acc[j]), 8, 64);
    acc[j] = acc[j] + __builtin_bit_cast(h2, b8);
    int b16 = __shfl_xor(__builtin_bit_cast(int, acc[j]), 16, 64);
    acc[j] = acc[j] + __builtin_bit_cast(h2, b16);
    int b32 = __shfl_xor(__builtin_bit_cast(int, acc[j]), 32, 64);
    acc[j] = acc[j] + __builtin_bit_cast(h2, b32);
  }
  const float4* op = (const float4*)(oacc + (size_t)node * 64 + fg * 8);
  float4 o0 = op[0], o1 = op[1];
  float v0 = (float)acc[0][0] + o0.x, v1 = (float)acc[0][1] + o0.y;
  float v2 = (float)acc[1][0] + o0.z, v3 = (float)acc[1][1] + o0.w;
  float v4 = (float)acc[2][0] + o1.x, v5 = (float)acc[2][1] + o1.y;
  float v6 = (float)acc[3][0] + o1.z, v7 = (float)acc[3][1] + o1.w;
  bool valid = fg < 5;  // feats 0..39
  float m01 = v0 > v1 ? v0 : v1, m23 = v2 > v3 ? v2 : v3;
  float m45 = v4 > v5 ? v4 : v5, m67 = v6 > v7 ? v6 : v7;
  float ml = m01 > m23 ? m01 : m23;
  float mh = m45 > m67 ? m45 : m67;
  float mv = ml > mh ? ml : mh;
  mv = valid ? mv : -1e30f;
#pragma unroll
  for (int o = 1; o <= 4; o <<= 1) {
    float t = __shfl_xor(mv, o, 64);
    mv = mv > t ? mv : t;
  }
  float se = 0.f;
  if (valid)
    se = __expf(v0 - mv) + __expf(v1 - mv) + __expf(v2 - mv) + __expf(v3 - mv) +
         __expf(v4 - mv) + __expf(v5 - mv) + __expf(v6 - mv) + __expf(v7 - mv);
#pragma unroll
  for (int o = 1; o <= 4; o <<= 1) se += __shfl_xor(se, o, 64);
  if (eg == 0 && valid) {
    float ls = mv + __logf(se);
    float4 r0 = make_float4(v0 - ls, v1 - ls, v2 - ls, v3 - ls);
    float4 r1 = make_float4(v4 - ls, v5 - ls, v6 - ls, v7 - ls);
    float4* wp = (float4*)(out + (size_t)node * 40 + fg * 8);
    wp[0] = r0;
    wp[1] = r1;
  }
}

extern "C" void kernel_launch(void* const* d_in, const int* in_sizes, int n_in,
                              void* d_out, int out_size, void* d_ws, size_t ws_size,
                              hipStream_t stream) {
  const float* x = (const float*)d_in[0];
  const int* esrc = (const int*)d_in[1];
  const int* edst = (const int*)d_in[2];
  const float* eval = (const float*)d_in[3];
  const float* W1 = (const float*)d_in[4];
  const float* b1 = (const float*)d_in[5];
  const float* Wr1 = (const float*)d_in[6];
  const float* br1 = (const float*)d_in[7];
  const float* W2 = (const float*)d_in[8];
  const float* b2 = (const float*)d_in[9];
  const float* Wr2 = (const float*)d_in[10];
  const float* br2 = (const float*)d_in[11];
  float* out = (float*)d_out;

  char* ws = (char*)d_ws;
  uint16_t* xb   = (uint16_t*)(ws);              // 51,200,000
  _Float16* S1h  = (_Float16*)(ws + 51200000);   // 12,800,000
  uint16_t* h    = (uint16_t*)(ws + 64000000);   // 25,600,000
  uint16_t* WT1  = (uint16_t*)(ws + 89600000);   //    262,144
  uint16_t* WT2  = (uint16_t*)(ws + 89862144);   //     65,536
  _Float16* S2h  = (_Float16*)(ws + 89927680);   //  6,400,000 (64-padded)
  float*    oacc = (float*)(ws + 96327680);      // 12,800,000 (64-padded)
  int*      counts = (int*)(ws + 109127680);     //    200,000
  int*      cursor = (int*)(ws + 109327680);     //    200,000
  int*      offs   = (int*)(ws + 109527680);     //    200,016 (padded for alignment)
  int2*     es     = (int2*)(ws + 109727696);    //  6,400,000
  int*      blocksums = (int*)(ws + 116127696);  //        784  (total ~116.13 MB)

  hipMemsetAsync(counts, 0, 400000, stream);  // counts + cursor (adjacent)

  k_pre<<<16265, 256, 0, stream>>>(x, xb, W1, Wr1, WT1, W2, Wr2, WT2, edst, counts);

  k_blocksum<<<NB, 256, 0, stream>>>(counts, blocksums);
  k_scan2<<<NB, 256, 0, stream>>>(counts, blocksums, offs);
  k_scatter<<<(N_EDGES + 255) / 256, 256, 0, stream>>>(esrc, edst, eval, offs, cursor, es);

  dim3 g1(391, 2);
  k_gemm1<<<g1, 256, 0, stream>>>(xb, WT1, N_NODES, S1h, h, br1);

  k_spmm1_csr<<<(N_NODES + 3) / 4, 256, 0, stream>>>(offs, es, S1h, b1, h);

  k_gemm2<<<391, 256, 0, stream>>>(h, WT2, N_NODES, S2h, oacc, b2, br2);

  k_spmm2_lsm<<<(N_NODES + 3) / 4, 256, 0, stream>>>(offs, es, S2h, oacc, out);
}

// Round 8
// 334.742 us; speedup vs baseline: 1.1427x; 1.0954x over previous
//
#include <hip/hip_runtime.h>
#include <stdint.h>

#define N_NODES 50000
#define N_EDGES 800000
#define NFEAT 512
#define NHID 128
#define NCLASS 40
#define NBLK 3125   // 800000 / 256 edge blocks
#define NBUCK 196   // ceil(50000/256) coarse dst buckets

typedef __attribute__((ext_vector_type(8))) __bf16 bf16x8;
typedef __attribute__((ext_vector_type(4))) float f32x4;
typedef _Float16 h2 __attribute__((ext_vector_type(2)));

__device__ __forceinline__ uint16_t f2b(float f) {
  uint32_t x = __float_as_uint(f);
  uint32_t r = (x + 0x7fffu + ((x >> 16) & 1u)) >> 16;
  return (uint16_t)r;
}

// ---------------- cast x (fp32 -> bf16), 8 elems/thread ----------------
__global__ void k_cast_x(const float* __restrict__ x, uint16_t* __restrict__ xb) {
  int i = blockIdx.x * 256 + threadIdx.x;  // 3,200,000 groups exactly
  const float4* p = (const float4*)x + (size_t)i * 2;
  float4 a = p[0], b = p[1];
  union { uint16_t u[8]; uint4 v; } o;
  o.u[0] = f2b(a.x); o.u[1] = f2b(a.y); o.u[2] = f2b(a.z); o.u[3] = f2b(a.w);
  o.u[4] = f2b(b.x); o.u[5] = f2b(b.y); o.u[6] = f2b(b.z); o.u[7] = f2b(b.w);
  ((uint4*)xb)[i] = o.v;
}

// ---------------- weight prep (merged, R4-proven): WT1[256][512], WT2[128][256] ----------------
__global__ void k_prep(const float* __restrict__ W1, const float* __restrict__ Wr1,
                       const float* __restrict__ W2, const float* __restrict__ Wr2,
                       uint16_t* __restrict__ WT1, uint16_t* __restrict__ WT2) {
  int idx = blockIdx.x * 256 + threadIdx.x;
  if (idx < 131072) {
    int n = idx >> 9, k = idx & 511;
    float v = (n < 128) ? W1[(size_t)k * 128 + n] : Wr1[(size_t)k * 128 + (n - 128)];
    WT1[idx] = f2b(v);
  } else {
    int j = idx - 131072;
    int n = j >> 8, k = j & 255;
    float v = 0.f;
    if (n < 40) v = W2[(size_t)k * 40 + n];
    else if (n < 80) v = Wr2[(size_t)k * 40 + (n - 40)];
    WT2[j] = f2b(v);
  }
}

// ---------------- P1: per-block coarse histogram (LDS atomics only) ----------------
__global__ void k_p1(const int* __restrict__ dst, int* __restrict__ bc) {
  __shared__ int hist[NBUCK];
  int t = threadIdx.x;
  if (t < NBUCK) hist[t] = 0;
  __syncthreads();
  int d = dst[blockIdx.x * 256 + t];
  atomicAdd(&hist[d >> 8], 1);
  __syncthreads();
  if (t < NBUCK) bc[blockIdx.x * NBUCK + t] = hist[t];  // coalesced [block][bucket]
}

// ---------------- P2: per-bucket scan over blocks: bc[b][k] -> bc2[k][b] excl, totals ----------------
__global__ void k_p2(const int* __restrict__ bc, int* __restrict__ bc2,
                     int* __restrict__ bucketTotal) {
  __shared__ int part[256];
  int k = blockIdx.x, t = threadIdx.x;
  int vals[13];
  int s = 0;
  int base = t * 13;
#pragma unroll
  for (int i = 0; i < 13; i++) {
    int idx = base + i;
    int v = (idx < NBLK) ? bc[idx * NBUCK + k] : 0;
    vals[i] = v;
    s += v;
  }
  part[t] = s;
  __syncthreads();
  for (int o = 1; o < 256; o <<= 1) {
    int v = (t >= o) ? part[t - o] : 0;
    __syncthreads();
    part[t] += v;
    __syncthreads();
  }
  int run = (t == 0) ? 0 : part[t - 1];
#pragma unroll
  for (int i = 0; i < 13; i++) {
    int idx = base + i;
    if (idx < NBLK) {
      bc2[k * NBLK + idx] = run;  // coalesced-ish sequential per block
      run += vals[i];
    }
  }
  if (t == 255) bucketTotal[k] = part[255];
}

// ---------------- P3: scan 196 bucket totals -> bucketBase[197] (1 small block) ----------------
__global__ void k_p3(const int* __restrict__ bucketTotal, int* __restrict__ bucketBase) {
  __shared__ int sc[256];
  int t = threadIdx.x;
  sc[t] = (t < NBUCK) ? bucketTotal[t] : 0;
  __syncthreads();
  for (int o = 1; o < 256; o <<= 1) {
    int v = (t >= o) ? sc[t - o] : 0;
    __syncthreads();
    sc[t] += v;
    __syncthreads();
  }
  if (t <= NBUCK) bucketBase[t] = (t == 0) ? 0 : sc[t - 1];
}

// ---------------- P4: coarse scatter, LDS cursors (no global atomics) ----------------
__global__ void k_p4(const int* __restrict__ src, const int* __restrict__ dst,
                     const float* __restrict__ val, const int* __restrict__ bc2,
                     const int* __restrict__ bucketBase, int2* __restrict__ esc) {
  __shared__ int start[NBUCK];
  __shared__ int cur[NBUCK];
  int b = blockIdx.x, t = threadIdx.x;
  if (t < NBUCK) {
    start[t] = bucketBase[t] + bc2[t * NBLK + b];
    cur[t] = 0;
  }
  __syncthreads();
  int e = b * 256 + t;
  int d = dst[e];
  int k = d >> 8;
  int r = atomicAdd(&cur[k], 1);  // LDS atomic
  esc[start[k] + r] = make_int2(src[e] | ((d & 255) << 16), __float_as_int(val[e]));
}

// ---------------- P5: per-bucket exact sort -> es (src,val) + offs per node ----------------
__global__ void k_p5(const int2* __restrict__ esc, const int* __restrict__ bucketBase,
                     int2* __restrict__ es, int* __restrict__ offs) {
  __shared__ int hist[256];
  __shared__ int sc[256];
  __shared__ int cur[256];
  int k = blockIdx.x, t = threadIdx.x;
  int base = bucketBase[k], n = bucketBase[k + 1] - base;
  hist[t] = 0;
  __syncthreads();
  for (int i = t; i < n; i += 256) atomicAdd(&hist[esc[base + i].x >> 16], 1);
  __syncthreads();
  sc[t] = hist[t];
  __syncthreads();
  for (int o = 1; o < 256; o <<= 1) {
    int v = (t >= o) ? sc[t - o] : 0;
    __syncthreads();
    sc[t] += v;
    __syncthreads();
  }
  int excl = (t == 0) ? 0 : sc[t - 1];
  int node = k * 256 + t;
  if (node <= N_NODES) offs[node] = base + excl;
  cur[t] = excl;
  __syncthreads();
  for (int i = t; i < n; i += 256) {
    int2 e = esc[base + i];
    int l = e.x >> 16;
    int r = atomicAdd(&cur[l], 1);  // LDS atomic
    es[base + r] = make_int2(e.x & 0xFFFF, e.y);
  }
}

// ---------------- GEMM1: xb(bf16) @ WT1^T, 128x128 tile, m97 structure (proven) ----------------
__global__ __launch_bounds__(256, 2) void k_gemm1(
    const uint16_t* __restrict__ A, const uint16_t* __restrict__ BT, int M,
    _Float16* __restrict__ S1h, uint16_t* __restrict__ h, const float* __restrict__ br1) {
  __shared__ uint16_t Al[128 * 64];
  __shared__ uint16_t Bl[128 * 64];
  const int tid = threadIdx.x;
  const int w = tid >> 6, lane = tid & 63;
  const int wm = w >> 1, wn = w & 1;
  const int m0 = blockIdx.x * 128;
  const int n0 = blockIdx.y * 128;
  const int K = NFEAT;

  f32x4 acc[4][4];
#pragma unroll
  for (int t = 0; t < 4; t++)
#pragma unroll
    for (int u = 0; u < 4; u++) acc[t][u] = (f32x4)0.f;

  const int lrow = lane >> 3;
  const int lcol = lane & 7;

  for (int kb = 0; kb < K / 64; ++kb) {
    __syncthreads();
    const int k0 = kb * 64;
#pragma unroll
    for (int i = 0; i < 4; i++) {
      int rr = (w * 4 + i) * 8 + lrow;
      int ra = m0 + rr;
      if (ra >= M) ra = M - 1;
      const uint16_t* gA = A + (size_t)ra * K + k0 + lcol * 8;
      __builtin_amdgcn_global_load_lds(
          (const __attribute__((address_space(1))) void*)gA,
          (__attribute__((address_space(3))) void*)&Al[(w * 4 + i) * 512], 16, 0, 0);
      int rb = n0 + rr;
      const uint16_t* gB = BT + (size_t)rb * K + k0 + lcol * 8;
      __builtin_amdgcn_global_load_lds(
          (const __attribute__((address_space(1))) void*)gB,
          (__attribute__((address_space(3))) void*)&Bl[(w * 4 + i) * 512], 16, 0, 0);
    }
    __syncthreads();
#pragma unroll
    for (int s = 0; s < 2; s++) {
      bf16x8 av[4], bv[4];
#pragma unroll
      for (int t = 0; t < 4; t++)
        av[t] = *(const bf16x8*)&Al[(wm * 64 + t * 16 + (lane & 15)) * 64 + s * 32 + (lane >> 4) * 8];
#pragma unroll
      for (int u = 0; u < 4; u++)
        bv[u] = *(const bf16x8*)&Bl[(wn * 64 + u * 16 + (lane & 15)) * 64 + s * 32 + (lane >> 4) * 8];
#pragma unroll
      for (int t = 0; t < 4; t++)
#pragma unroll
        for (int u = 0; u < 4; u++)
          acc[t][u] = __builtin_amdgcn_mfma_f32_16x16x32_bf16(av[t], bv[u], acc[t][u], 0, 0, 0);
    }
  }

  const int cl = lane & 15, rq = lane >> 4;
#pragma unroll
  for (int t = 0; t < 4; t++) {
#pragma unroll
    for (int u = 0; u < 4; u++) {
#pragma unroll
      for (int r = 0; r < 4; r++) {
        int m = m0 + wm * 64 + t * 16 + rq * 4 + r;
        int n = n0 + wn * 64 + u * 16 + cl;
        if (m >= M) continue;
        float v = acc[t][u][r];
        if (n < 128)
          S1h[(size_t)m * 128 + n] = (_Float16)v;  // x@W1 (b1 added post-spmm)
        else
          h[(size_t)m * 256 + n] = f2b(v + br1[n - 128]);  // h right = x@Wr1+br1
      }
    }
  }
}

// ---------------- GEMM2: h(bf16) @ WT2^T, 128x128 tile, f16 S2 + padded epilogue (proven) ----------------
__global__ __launch_bounds__(256, 2) void k_gemm2(
    const uint16_t* __restrict__ A, const uint16_t* __restrict__ BT, int M,
    _Float16* __restrict__ S2h, float* __restrict__ oacc,
    const float* __restrict__ b2, const float* __restrict__ br2) {
  __shared__ uint16_t Al[128 * 64];
  __shared__ uint16_t Bl[128 * 64];
  const int tid = threadIdx.x;
  const int w = tid >> 6, lane = tid & 63;
  const int wm = w >> 1, wn = w & 1;
  const int m0 = blockIdx.x * 128;
  const int K = 256;

  f32x4 acc[4][4];
#pragma unroll
  for (int t = 0; t < 4; t++)
#pragma unroll
    for (int u = 0; u < 4; u++) acc[t][u] = (f32x4)0.f;

  const int lrow = lane >> 3;
  const int lcol = lane & 7;

  for (int kb = 0; kb < K / 64; ++kb) {
    __syncthreads();
    const int k0 = kb * 64;
#pragma unroll
    for (int i = 0; i < 4; i++) {
      int rr = (w * 4 + i) * 8 + lrow;
      int ra = m0 + rr;
      if (ra >= M) ra = M - 1;
      const uint16_t* gA = A + (size_t)ra * K + k0 + lcol * 8;
      __builtin_amdgcn_global_load_lds(
          (const __attribute__((address_space(1))) void*)gA,
          (__attribute__((address_space(3))) void*)&Al[(w * 4 + i) * 512], 16, 0, 0);
      const uint16_t* gB = BT + (size_t)rr * K + k0 + lcol * 8;
      __builtin_amdgcn_global_load_lds(
          (const __attribute__((address_space(1))) void*)gB,
          (__attribute__((address_space(3))) void*)&Bl[(w * 4 + i) * 512], 16, 0, 0);
    }
    __syncthreads();
#pragma unroll
    for (int s = 0; s < 2; s++) {
      bf16x8 av[4], bv[4];
#pragma unroll
      for (int t = 0; t < 4; t++)
        av[t] = *(const bf16x8*)&Al[(wm * 64 + t * 16 + (lane & 15)) * 64 + s * 32 + (lane >> 4) * 8];
#pragma unroll
      for (int u = 0; u < 4; u++)
        bv[u] = *(const bf16x8*)&Bl[(wn * 64 + u * 16 + (lane & 15)) * 64 + s * 32 + (lane >> 4) * 8];
#pragma unroll
      for (int t = 0; t < 4; t++)
#pragma unroll
        for (int u = 0; u < 4; u++)
          acc[t][u] = __builtin_amdgcn_mfma_f32_16x16x32_bf16(av[t], bv[u], acc[t][u], 0, 0, 0);
    }
  }

  const int cl = lane & 15, rq = lane >> 4;
#pragma unroll
  for (int t = 0; t < 4; t++) {
#pragma unroll
    for (int u = 0; u < 4; u++) {
#pragma unroll
      for (int r = 0; r < 4; r++) {
        int m = m0 + wm * 64 + t * 16 + rq * 4 + r;
        int n = wn * 64 + u * 16 + cl;
        if (m >= M) continue;
        float v = acc[t][u][r];
        if (n < 40) S2h[(size_t)m * 64 + n] = (_Float16)v;
        else if (n < 64) S2h[(size_t)m * 64 + n] = (_Float16)0.f;
        if (n >= 40 && n < 80) oacc[(size_t)m * 64 + (n - 40)] = v + b2[n - 40] + br2[n - 40];
        else if (n >= 80 && n < 104) oacc[(size_t)m * 64 + (n - 40)] = 0.f;
      }
    }
  }
}

// ---------------- SpMM1 via CSR: wave/node, 4 edges/iter, f16 packed FMA (proven) ----------------
__global__ void k_spmm1_csr(const int* __restrict__ offs, const int2* __restrict__ es,
                            const _Float16* __restrict__ S1h, const float* __restrict__ b1,
                            uint16_t* __restrict__ h) {
  int node = blockIdx.x * 4 + (threadIdx.x >> 6);
  if (node >= N_NODES) return;
  int lane = threadIdx.x & 63;
  int eg = lane >> 4;  // 0..3 edge slot
  int fg = lane & 15;  // 0..15 feat group (8 feats)
  int beg = offs[node], end = offs[node + 1];
  h2 acc[4];
#pragma unroll
  for (int j = 0; j < 4; j++) acc[j] = (h2)(_Float16)0.f;
  for (int p = beg; p < end; p += 4) {
    int pe = p + eg;
    bool ok = pe < end;
    int2 ev = es[ok ? pe : beg];
    float v = ok ? __int_as_float(ev.y) : 0.f;
    _Float16 vh = (_Float16)v;
    h2 vv = {vh, vh};
    uint4 g = *(const uint4*)(S1h + (size_t)ev.x * 128 + fg * 8);
    h2* hp = (h2*)&g;
#pragma unroll
    for (int j = 0; j < 4; j++) acc[j] = vv * hp[j] + acc[j];
  }
#pragma unroll
  for (int j = 0; j < 4; j++) {
    int b16 = __shfl_xor(__builtin_bit_cast(int, acc[j]), 16, 64);
    acc[j] = acc[j] + __builtin_bit_cast(h2, b16);
    int b32 = __shfl_xor(__builtin_bit_cast(int, acc[j]), 32, 64);
    acc[j] = acc[j] + __builtin_bit_cast(h2, b32);
  }
  if (eg == 0) {
    const float4* bp = (const float4*)(b1 + fg * 8);
    float4 ba = bp[0], bb = bp[1];
    float r0 = (float)acc[0][0] + ba.x, r1 = (float)acc[0][1] + ba.y;
    float r2 = (float)acc[1][0] + ba.z, r3 = (float)acc[1][1] + ba.w;
    float r4 = (float)acc[2][0] + bb.x, r5 = (float)acc[2][1] + bb.y;
    float r6 = (float)acc[3][0] + bb.z, r7 = (float)acc[3][1] + bb.w;
    union { uint16_t u[8]; uint4 v; } o;
    o.u[0] = f2b(r0 > 0.f ? r0 : 0.f); o.u[1] = f2b(r1 > 0.f ? r1 : 0.f);
    o.u[2] = f2b(r2 > 0.f ? r2 : 0.f); o.u[3] = f2b(r3 > 0.f ? r3 : 0.f);
    o.u[4] = f2b(r4 > 0.f ? r4 : 0.f); o.u[5] = f2b(r5 > 0.f ? r5 : 0.f);
    o.u[6] = f2b(r6 > 0.f ? r6 : 0.f); o.u[7] = f2b(r7 > 0.f ? r7 : 0.f);
    *(uint4*)(h + (size_t)node * 256 + fg * 8) = o.v;
  }
}

// ---------------- SpMM2 via CSR + log_softmax: wave/node, 8 edges/iter, f16 packed (proven) ----------------
__global__ void k_spmm2_lsm(const int* __restrict__ offs, const int2* __restrict__ es,
                            const _Float16* __restrict__ S2h, const float* __restrict__ oacc,
                            float* __restrict__ out) {
  int node = blockIdx.x * 4 + (threadIdx.x >> 6);
  if (node >= N_NODES) return;
  int lane = threadIdx.x & 63;
  int eg = lane >> 3;  // 0..7 edge slot
  int fg = lane & 7;   // 0..7 feat group (8 feats of 64-padded row)
  int beg = offs[node], end = offs[node + 1];
  h2 acc[4];
#pragma unroll
  for (int j = 0; j < 4; j++) acc[j] = (h2)(_Float16)0.f;
  for (int p = beg; p < end; p += 8) {
    int pe = p + eg;
    bool ok = pe < end;
    int2 ev = es[ok ? pe : beg];
    float v = ok ? __int_as_float(ev.y) : 0.f;
    _Float16 vh = (_Float16)v;
    h2 vv = {vh, vh};
    uint4 g = *(const uint4*)(S2h + (size_t)ev.x * 64 + fg * 8);
    h2* hp = (h2*)&g;
#pragma unroll
    for (int j = 0; j < 4; j++) acc[j] = vv * hp[j] + acc[j];
  }
#pragma unroll
  for (int j = 0; j < 4; j++) {
    int b8 = __shfl_xor(__builtin_bit_cast(int, acc[j]), 8, 64);
    acc[j] = acc[j] + __builtin_bit_cast(h2, b8);
    int b16 = __shfl_xor(__builtin_bit_cast(int, acc[j]), 16, 64);
    acc[j] = acc[j] + __builtin_bit_cast(h2, b16);
    int b32 = __shfl_xor(__builtin_bit_cast(int, acc[j]), 32, 64);
    acc[j] = acc[j] + __builtin_bit_cast(h2, b32);
  }
  const float4* op = (const float4*)(oacc + (size_t)node * 64 + fg * 8);
  float4 o0 = op[0], o1 = op[1];
  float v0 = (float)acc[0][0] + o0.x, v1 = (float)acc[0][1] + o0.y;
  float v2 = (float)acc[1][0] + o0.z, v3 = (float)acc[1][1] + o0.w;
  float v4 = (float)acc[2][0] + o1.x, v5 = (float)acc[2][1] + o1.y;
  float v6 = (float)acc[3][0] + o1.z, v7 = (float)acc[3][1] + o1.w;
  bool valid = fg < 5;  // feats 0..39
  float m01 = v0 > v1 ? v0 : v1, m23 = v2 > v3 ? v2 : v3;
  float m45 = v4 > v5 ? v4 : v5, m67 = v6 > v7 ? v6 : v7;
  float ml = m01 > m23 ? m01 : m23;
  float mh = m45 > m67 ? m45 : m67;
  float mv = ml > mh ? ml : mh;
  mv = valid ? mv : -1e30f;
#pragma unroll
  for (int o = 1; o <= 4; o <<= 1) {
    float t = __shfl_xor(mv, o, 64);
    mv = mv > t ? mv : t;
  }
  float se = 0.f;
  if (valid)
    se = __expf(v0 - mv) + __expf(v1 - mv) + __expf(v2 - mv) + __expf(v3 - mv) +
         __expf(v4 - mv) + __expf(v5 - mv) + __expf(v6 - mv) + __expf(v7 - mv);
#pragma unroll
  for (int o = 1; o <= 4; o <<= 1) se += __shfl_xor(se, o, 64);
  if (eg == 0 && valid) {
    float ls = mv + __logf(se);
    float4 r0 = make_float4(v0 - ls, v1 - ls, v2 - ls, v3 - ls);
    float4 r1 = make_float4(v4 - ls, v5 - ls, v6 - ls, v7 - ls);
    float4* wp = (float4*)(out + (size_t)node * 40 + fg * 8);
    wp[0] = r0;
    wp[1] = r1;
  }
}

extern "C" void kernel_launch(void* const* d_in, const int* in_sizes, int n_in,
                              void* d_out, int out_size, void* d_ws, size_t ws_size,
                              hipStream_t stream) {
  const float* x = (const float*)d_in[0];
  const int* esrc = (const int*)d_in[1];
  const int* edst = (const int*)d_in[2];
  const float* eval = (const float*)d_in[3];
  const float* W1 = (const float*)d_in[4];
  const float* b1 = (const float*)d_in[5];
  const float* Wr1 = (const float*)d_in[6];
  const float* br1 = (const float*)d_in[7];
  const float* W2 = (const float*)d_in[8];
  const float* b2 = (const float*)d_in[9];
  const float* Wr2 = (const float*)d_in[10];
  const float* br2 = (const float*)d_in[11];
  float* out = (float*)d_out;

  char* ws = (char*)d_ws;
  uint16_t* xb   = (uint16_t*)(ws);              // 51,200,000
  _Float16* S1h  = (_Float16*)(ws + 51200000);   // 12,800,000
  uint16_t* h    = (uint16_t*)(ws + 64000000);   // 25,600,000
  uint16_t* WT1  = (uint16_t*)(ws + 89600000);   //    262,144
  uint16_t* WT2  = (uint16_t*)(ws + 89862144);   //     65,536
  _Float16* S2h  = (_Float16*)(ws + 89927680);   //  6,400,000 (64-padded)
  float*    oacc = (float*)(ws + 96327680);      // 12,800,000 (64-padded)
  int*      offs = (int*)(ws + 109127680);       //    200,016 (padded)
  int2*     es   = (int2*)(ws + 109327696);      //  6,400,000
  int2*     esc  = (int2*)(ws + 115727696);      //  6,400,000
  int*      bc   = (int*)(ws + 122127696);       //  2,450,000 ([block][bucket])
  int*      bc2  = (int*)(ws + 124577696);       //  2,450,000 ([bucket][block])
  int*      bucketTotal = (int*)(ws + 127027696);//        784
  int*      bucketBase  = (int*)(ws + 127028480);//        788  (total ~127 MB)

  k_cast_x<<<12500, 256, 0, stream>>>(x, xb);
  k_prep<<<640, 256, 0, stream>>>(W1, Wr1, W2, Wr2, WT1, WT2);

  k_p1<<<NBLK, 256, 0, stream>>>(edst, bc);
  k_p2<<<NBUCK, 256, 0, stream>>>(bc, bc2, bucketTotal);
  k_p3<<<1, 256, 0, stream>>>(bucketTotal, bucketBase);
  k_p4<<<NBLK, 256, 0, stream>>>(esrc, edst, eval, bc2, bucketBase, esc);
  k_p5<<<NBUCK, 256, 0, stream>>>(esc, bucketBase, es, offs);

  dim3 g1(391, 2);
  k_gemm1<<<g1, 256, 0, stream>>>(xb, WT1, N_NODES, S1h, h, br1);

  k_spmm1_csr<<<(N_NODES + 3) / 4, 256, 0, stream>>>(offs, es, S1h, b1, h);

  k_gemm2<<<391, 256, 0, stream>>>(h, WT2, N_NODES, S2h, oacc, b2, br2);

  k_spmm2_lsm<<<(N_NODES + 3) / 4, 256, 0, stream>>>(offs, es, S2h, oacc, out);
}

// Round 9
// 319.950 us; speedup vs baseline: 1.1955x; 1.0462x over previous
//
#include <hip/hip_runtime.h>
#include <stdint.h>

#define N_NODES 50000
#define N_EDGES 800000
#define NFEAT 512
#define NHID 128
#define NCLASS 40
#define NBLK 3125   // 800000 / 256 edge blocks
#define NBUCK 196   // ceil(50000/256) coarse dst buckets

typedef __attribute__((ext_vector_type(8))) __bf16 bf16x8;
typedef __attribute__((ext_vector_type(4))) float f32x4;
typedef _Float16 h2 __attribute__((ext_vector_type(2)));

__device__ __forceinline__ uint16_t f2b(float f) {
  uint32_t x = __float_as_uint(f);
  uint32_t r = (x + 0x7fffu + ((x >> 16) & 1u)) >> 16;
  return (uint16_t)r;
}

// ---------------- merged prologue: cast x | prep WT1/WT2 | p1 coarse hist ----------------
// blocks [0,12500): cast | [12500,13140): weight prep | [13140,16265): p1 (LDS atomics only)
__global__ void k_pre2(const float* __restrict__ x, uint16_t* __restrict__ xb,
                       const float* __restrict__ W1, const float* __restrict__ Wr1,
                       const float* __restrict__ W2, const float* __restrict__ Wr2,
                       uint16_t* __restrict__ WT1, uint16_t* __restrict__ WT2,
                       const int* __restrict__ dst, int* __restrict__ bc) {
  int b = blockIdx.x, t = threadIdx.x;
  if (b < 12500) {
    int i = b * 256 + t;  // 3,200,000 groups exactly
    const float4* p = (const float4*)x + (size_t)i * 2;
    float4 a = p[0], c = p[1];
    union { uint16_t u[8]; uint4 v; } o;
    o.u[0] = f2b(a.x); o.u[1] = f2b(a.y); o.u[2] = f2b(a.z); o.u[3] = f2b(a.w);
    o.u[4] = f2b(c.x); o.u[5] = f2b(c.y); o.u[6] = f2b(c.z); o.u[7] = f2b(c.w);
    ((uint4*)xb)[i] = o.v;
  } else if (b < 13140) {
    int idx = (b - 12500) * 256 + t;
    if (idx < 131072) {
      int n = idx >> 9, k = idx & 511;
      float v = (n < 128) ? W1[(size_t)k * 128 + n] : Wr1[(size_t)k * 128 + (n - 128)];
      WT1[idx] = f2b(v);
    } else {
      int j = idx - 131072;
      int n = j >> 8, k = j & 255;
      float v = 0.f;
      if (n < 40) v = W2[(size_t)k * 40 + n];
      else if (n < 80) v = Wr2[(size_t)k * 40 + (n - 40)];
      WT2[j] = f2b(v);
    }
  } else {
    __shared__ int hist[NBUCK];
    int eb = b - 13140;  // 0..3124
    if (t < NBUCK) hist[t] = 0;
    __syncthreads();
    int d = dst[eb * 256 + t];
    atomicAdd(&hist[d >> 8], 1);
    __syncthreads();
    if (t < NBUCK) bc[eb * NBUCK + t] = hist[t];
  }
}

// ---------------- P2: per-bucket scan over blocks: bc[b][k] -> bc2[k][b] excl, totals ----------------
__global__ void k_p2(const int* __restrict__ bc, int* __restrict__ bc2,
                     int* __restrict__ bucketTotal) {
  __shared__ int part[256];
  int k = blockIdx.x, t = threadIdx.x;
  int vals[13];
  int s = 0;
  int base = t * 13;
#pragma unroll
  for (int i = 0; i < 13; i++) {
    int idx = base + i;
    int v = (idx < NBLK) ? bc[idx * NBUCK + k] : 0;
    vals[i] = v;
    s += v;
  }
  part[t] = s;
  __syncthreads();
  for (int o = 1; o < 256; o <<= 1) {
    int v = (t >= o) ? part[t - o] : 0;
    __syncthreads();
    part[t] += v;
    __syncthreads();
  }
  int run = (t == 0) ? 0 : part[t - 1];
#pragma unroll
  for (int i = 0; i < 13; i++) {
    int idx = base + i;
    if (idx < NBLK) {
      bc2[k * NBLK + idx] = run;
      run += vals[i];
    }
  }
  if (t == 255) bucketTotal[k] = part[255];
}

// ---------------- P4: coarse scatter, inline bucket-base scan, LDS cursors ----------------
__global__ void k_p4(const int* __restrict__ src, const int* __restrict__ dst,
                     const float* __restrict__ val, const int* __restrict__ bc2,
                     const int* __restrict__ bucketTotal, int2* __restrict__ esc) {
  __shared__ int sc[256];
  __shared__ int start[NBUCK];
  __shared__ int cur[NBUCK];
  int b = blockIdx.x, t = threadIdx.x;
  sc[t] = (t < NBUCK) ? bucketTotal[t] : 0;
  __syncthreads();
  for (int o = 1; o < 256; o <<= 1) {
    int v = (t >= o) ? sc[t - o] : 0;
    __syncthreads();
    sc[t] += v;
    __syncthreads();
  }
  if (t < NBUCK) {
    start[t] = ((t == 0) ? 0 : sc[t - 1]) + bc2[t * NBLK + b];
    cur[t] = 0;
  }
  __syncthreads();
  int e = b * 256 + t;
  int d = dst[e];
  int k = d >> 8;
  int r = atomicAdd(&cur[k], 1);  // LDS atomic
  esc[start[k] + r] = make_int2(src[e] | ((d & 255) << 16), __float_as_int(val[e]));
}

// ---------------- P5: per-bucket exact sort (inline bucket-base scan) -> es + offs ----------------
__global__ void k_p5(const int2* __restrict__ esc, const int* __restrict__ bucketTotal,
                     int2* __restrict__ es, int* __restrict__ offs) {
  __shared__ int bsc[256];
  __shared__ int hist[256];
  __shared__ int sc[256];
  __shared__ int cur[256];
  int k = blockIdx.x, t = threadIdx.x;
  bsc[t] = (t < NBUCK) ? bucketTotal[t] : 0;
  __syncthreads();
  for (int o = 1; o < 256; o <<= 1) {
    int v = (t >= o) ? bsc[t - o] : 0;
    __syncthreads();
    bsc[t] += v;
    __syncthreads();
  }
  int base = (k == 0) ? 0 : bsc[k - 1];
  int n = bsc[k] - base;
  hist[t] = 0;
  __syncthreads();
  for (int i = t; i < n; i += 256) atomicAdd(&hist[esc[base + i].x >> 16], 1);
  __syncthreads();
  sc[t] = hist[t];
  __syncthreads();
  for (int o = 1; o < 256; o <<= 1) {
    int v = (t >= o) ? sc[t - o] : 0;
    __syncthreads();
    sc[t] += v;
    __syncthreads();
  }
  int excl = (t == 0) ? 0 : sc[t - 1];
  int node = k * 256 + t;
  if (node <= N_NODES) offs[node] = base + excl;
  cur[t] = excl;
  __syncthreads();
  for (int i = t; i < n; i += 256) {
    int2 e = esc[base + i];
    int l = e.x >> 16;
    int r = atomicAdd(&cur[l], 1);  // LDS atomic
    es[base + r] = make_int2(e.x & 0xFFFF, e.y);
  }
}

// ---------------- GEMM1: xb(bf16) @ WT1^T, 128x128 tile, m97 structure (proven) ----------------
__global__ __launch_bounds__(256, 2) void k_gemm1(
    const uint16_t* __restrict__ A, const uint16_t* __restrict__ BT, int M,
    _Float16* __restrict__ S1h, uint16_t* __restrict__ h, const float* __restrict__ br1) {
  __shared__ uint16_t Al[128 * 64];
  __shared__ uint16_t Bl[128 * 64];
  const int tid = threadIdx.x;
  const int w = tid >> 6, lane = tid & 63;
  const int wm = w >> 1, wn = w & 1;
  const int m0 = blockIdx.x * 128;
  const int n0 = blockIdx.y * 128;
  const int K = NFEAT;

  f32x4 acc[4][4];
#pragma unroll
  for (int t = 0; t < 4; t++)
#pragma unroll
    for (int u = 0; u < 4; u++) acc[t][u] = (f32x4)0.f;

  const int lrow = lane >> 3;
  const int lcol = lane & 7;

  for (int kb = 0; kb < K / 64; ++kb) {
    __syncthreads();
    const int k0 = kb * 64;
#pragma unroll
    for (int i = 0; i < 4; i++) {
      int rr = (w * 4 + i) * 8 + lrow;
      int ra = m0 + rr;
      if (ra >= M) ra = M - 1;
      const uint16_t* gA = A + (size_t)ra * K + k0 + lcol * 8;
      __builtin_amdgcn_global_load_lds(
          (const __attribute__((address_space(1))) void*)gA,
          (__attribute__((address_space(3))) void*)&Al[(w * 4 + i) * 512], 16, 0, 0);
      int rb = n0 + rr;
      const uint16_t* gB = BT + (size_t)rb * K + k0 + lcol * 8;
      __builtin_amdgcn_global_load_lds(
          (const __attribute__((address_space(1))) void*)gB,
          (__attribute__((address_space(3))) void*)&Bl[(w * 4 + i) * 512], 16, 0, 0);
    }
    __syncthreads();
#pragma unroll
    for (int s = 0; s < 2; s++) {
      bf16x8 av[4], bv[4];
#pragma unroll
      for (int t = 0; t < 4; t++)
        av[t] = *(const bf16x8*)&Al[(wm * 64 + t * 16 + (lane & 15)) * 64 + s * 32 + (lane >> 4) * 8];
#pragma unroll
      for (int u = 0; u < 4; u++)
        bv[u] = *(const bf16x8*)&Bl[(wn * 64 + u * 16 + (lane & 15)) * 64 + s * 32 + (lane >> 4) * 8];
#pragma unroll
      for (int t = 0; t < 4; t++)
#pragma unroll
        for (int u = 0; u < 4; u++)
          acc[t][u] = __builtin_amdgcn_mfma_f32_16x16x32_bf16(av[t], bv[u], acc[t][u], 0, 0, 0);
    }
  }

  const int cl = lane & 15, rq = lane >> 4;
#pragma unroll
  for (int t = 0; t < 4; t++) {
#pragma unroll
    for (int u = 0; u < 4; u++) {
#pragma unroll
      for (int r = 0; r < 4; r++) {
        int m = m0 + wm * 64 + t * 16 + rq * 4 + r;
        int n = n0 + wn * 64 + u * 16 + cl;
        if (m >= M) continue;
        float v = acc[t][u][r];
        if (n < 128)
          S1h[(size_t)m * 128 + n] = (_Float16)v;  // x@W1 (b1 added post-spmm)
        else
          h[(size_t)m * 256 + n] = f2b(v + br1[n - 128]);  // h right = x@Wr1+br1
      }
    }
  }
}

// ---------------- GEMM2: h(bf16) @ WT2^T, 128x128 tile, f16 S2 + padded epilogue (proven) ----------------
__global__ __launch_bounds__(256, 2) void k_gemm2(
    const uint16_t* __restrict__ A, const uint16_t* __restrict__ BT, int M,
    _Float16* __restrict__ S2h, float* __restrict__ oacc,
    const float* __restrict__ b2, const float* __restrict__ br2) {
  __shared__ uint16_t Al[128 * 64];
  __shared__ uint16_t Bl[128 * 64];
  const int tid = threadIdx.x;
  const int w = tid >> 6, lane = tid & 63;
  const int wm = w >> 1, wn = w & 1;
  const int m0 = blockIdx.x * 128;
  const int K = 256;

  f32x4 acc[4][4];
#pragma unroll
  for (int t = 0; t < 4; t++)
#pragma unroll
    for (int u = 0; u < 4; u++) acc[t][u] = (f32x4)0.f;

  const int lrow = lane >> 3;
  const int lcol = lane & 7;

  for (int kb = 0; kb < K / 64; ++kb) {
    __syncthreads();
    const int k0 = kb * 64;
#pragma unroll
    for (int i = 0; i < 4; i++) {
      int rr = (w * 4 + i) * 8 + lrow;
      int ra = m0 + rr;
      if (ra >= M) ra = M - 1;
      const uint16_t* gA = A + (size_t)ra * K + k0 + lcol * 8;
      __builtin_amdgcn_global_load_lds(
          (const __attribute__((address_space(1))) void*)gA,
          (__attribute__((address_space(3))) void*)&Al[(w * 4 + i) * 512], 16, 0, 0);
      const uint16_t* gB = BT + (size_t)rr * K + k0 + lcol * 8;
      __builtin_amdgcn_global_load_lds(
          (const __attribute__((address_space(1))) void*)gB,
          (__attribute__((address_space(3))) void*)&Bl[(w * 4 + i) * 512], 16, 0, 0);
    }
    __syncthreads();
#pragma unroll
    for (int s = 0; s < 2; s++) {
      bf16x8 av[4], bv[4];
#pragma unroll
      for (int t = 0; t < 4; t++)
        av[t] = *(const bf16x8*)&Al[(wm * 64 + t * 16 + (lane & 15)) * 64 + s * 32 + (lane >> 4) * 8];
#pragma unroll
      for (int u = 0; u < 4; u++)
        bv[u] = *(const bf16x8*)&Bl[(wn * 64 + u * 16 + (lane & 15)) * 64 + s * 32 + (lane >> 4) * 8];
#pragma unroll
      for (int t = 0; t < 4; t++)
#pragma unroll
        for (int u = 0; u < 4; u++)
          acc[t][u] = __builtin_amdgcn_mfma_f32_16x16x32_bf16(av[t], bv[u], acc[t][u], 0, 0, 0);
    }
  }

  const int cl = lane & 15, rq = lane >> 4;
#pragma unroll
  for (int t = 0; t < 4; t++) {
#pragma unroll
    for (int u = 0; u < 4; u++) {
#pragma unroll
      for (int r = 0; r < 4; r++) {
        int m = m0 + wm * 64 + t * 16 + rq * 4 + r;
        int n = wn * 64 + u * 16 + cl;
        if (m >= M) continue;
        float v = acc[t][u][r];
        if (n < 40) S2h[(size_t)m * 64 + n] = (_Float16)v;
        else if (n < 64) S2h[(size_t)m * 64 + n] = (_Float16)0.f;
        if (n >= 40 && n < 80) oacc[(size_t)m * 64 + (n - 40)] = v + b2[n - 40] + br2[n - 40];
        else if (n >= 80 && n < 104) oacc[(size_t)m * 64 + (n - 40)] = 0.f;
      }
    }
  }
}

// ---------------- SpMM1 via CSR: wave/node, 8 edges/iter (2 gathers in flight) ----------------
__global__ void k_spmm1_csr(const int* __restrict__ offs, const int2* __restrict__ es,
                            const _Float16* __restrict__ S1h, const float* __restrict__ b1,
                            uint16_t* __restrict__ h) {
  int node = blockIdx.x * 4 + (threadIdx.x >> 6);
  if (node >= N_NODES) return;
  int lane = threadIdx.x & 63;
  int eg = lane >> 4;  // 0..3 edge slot
  int fg = lane & 15;  // 0..15 feat group (8 feats)
  int beg = offs[node], end = offs[node + 1];
  h2 acc[4];
#pragma unroll
  for (int j = 0; j < 4; j++) acc[j] = (h2)(_Float16)0.f;
  for (int p = beg; p < end; p += 8) {
    int pa = p + eg, pb = p + 4 + eg;
    bool oka = pa < end, okb = pb < end;
    int2 ea = es[oka ? pa : beg];
    int2 eb = es[okb ? pb : beg];
    float va = oka ? __int_as_float(ea.y) : 0.f;
    float vb = okb ? __int_as_float(eb.y) : 0.f;
    _Float16 vah = (_Float16)va, vbh = (_Float16)vb;
    h2 vva = {vah, vah}, vvb = {vbh, vbh};
    uint4 ga = *(const uint4*)(S1h + (size_t)ea.x * 128 + fg * 8);
    uint4 gb = *(const uint4*)(S1h + (size_t)eb.x * 128 + fg * 8);
    h2* ha = (h2*)&ga;
    h2* hb = (h2*)&gb;
#pragma unroll
    for (int j = 0; j < 4; j++) {
      acc[j] = vva * ha[j] + acc[j];
      acc[j] = vvb * hb[j] + acc[j];
    }
  }
#pragma unroll
  for (int j = 0; j < 4; j++) {
    int b16 = __shfl_xor(__builtin_bit_cast(int, acc[j]), 16, 64);
    acc[j] = acc[j] + __builtin_bit_cast(h2, b16);
    int b32 = __shfl_xor(__builtin_bit_cast(int, acc[j]), 32, 64);
    acc[j] = acc[j] + __builtin_bit_cast(h2, b32);
  }
  if (eg == 0) {
    const float4* bp = (const float4*)(b1 + fg * 8);
    float4 ba = bp[0], bb = bp[1];
    float r0 = (float)acc[0][0] + ba.x, r1 = (float)acc[0][1] + ba.y;
    float r2 = (float)acc[1][0] + ba.z, r3 = (float)acc[1][1] + ba.w;
    float r4 = (float)acc[2][0] + bb.x, r5 = (float)acc[2][1] + bb.y;
    float r6 = (float)acc[3][0] + bb.z, r7 = (float)acc[3][1] + bb.w;
    union { uint16_t u[8]; uint4 v; } o;
    o.u[0] = f2b(r0 > 0.f ? r0 : 0.f); o.u[1] = f2b(r1 > 0.f ? r1 : 0.f);
    o.u[2] = f2b(r2 > 0.f ? r2 : 0.f); o.u[3] = f2b(r3 > 0.f ? r3 : 0.f);
    o.u[4] = f2b(r4 > 0.f ? r4 : 0.f); o.u[5] = f2b(r5 > 0.f ? r5 : 0.f);
    o.u[6] = f2b(r6 > 0.f ? r6 : 0.f); o.u[7] = f2b(r7 > 0.f ? r7 : 0.f);
    *(uint4*)(h + (size_t)node * 256 + fg * 8) = o.v;
  }
}

// ---------------- SpMM2 via CSR + log_softmax: wave/node, 16 edges/iter ----------------
__global__ void k_spmm2_lsm(const int* __restrict__ offs, const int2* __restrict__ es,
                            const _Float16* __restrict__ S2h, const float* __restrict__ oacc,
                            float* __restrict__ out) {
  int node = blockIdx.x * 4 + (threadIdx.x >> 6);
  if (node >= N_NODES) return;
  int lane = threadIdx.x & 63;
  int eg = lane >> 3;  // 0..7 edge slot
  int fg = lane & 7;   // 0..7 feat group (8 feats of 64-padded row)
  int beg = offs[node], end = offs[node + 1];
  h2 acc[4];
#pragma unroll
  for (int j = 0; j < 4; j++) acc[j] = (h2)(_Float16)0.f;
  for (int p = beg; p < end; p += 16) {
    int pa = p + eg, pb = p + 8 + eg;
    bool oka = pa < end, okb = pb < end;
    int2 ea = es[oka ? pa : beg];
    int2 eb = es[okb ? pb : beg];
    float va = oka ? __int_as_float(ea.y) : 0.f;
    float vb = okb ? __int_as_float(eb.y) : 0.f;
    _Float16 vah = (_Float16)va, vbh = (_Float16)vb;
    h2 vva = {vah, vah}, vvb = {vbh, vbh};
    uint4 ga = *(const uint4*)(S2h + (size_t)ea.x * 64 + fg * 8);
    uint4 gb = *(const uint4*)(S2h + (size_t)eb.x * 64 + fg * 8);
    h2* ha = (h2*)&ga;
    h2* hb = (h2*)&gb;
#pragma unroll
    for (int j = 0; j < 4; j++) {
      acc[j] = vva * ha[j] + acc[j];
      acc[j] = vvb * hb[j] + acc[j];
    }
  }
#pragma unroll
  for (int j = 0; j < 4; j++) {
    int b8 = __shfl_xor(__builtin_bit_cast(int, acc[j]), 8, 64);
    acc[j] = acc[j] + __builtin_bit_cast(h2, b8);
    int b16 = __shfl_xor(__builtin_bit_cast(int, acc[j]), 16, 64);
    acc[j] = acc[j] + __builtin_bit_cast(h2, b16);
    int b32 = __shfl_xor(__builtin_bit_cast(int, acc[j]), 32, 64);
    acc[j] = acc[j] + __builtin_bit_cast(h2, b32);
  }
  const float4* op = (const float4*)(oacc + (size_t)node * 64 + fg * 8);
  float4 o0 = op[0], o1 = op[1];
  float v0 = (float)acc[0][0] + o0.x, v1 = (float)acc[0][1] + o0.y;
  float v2 = (float)acc[1][0] + o0.z, v3 = (float)acc[1][1] + o0.w;
  float v4 = (float)acc[2][0] + o1.x, v5 = (float)acc[2][1] + o1.y;
  float v6 = (float)acc[3][0] + o1.z, v7 = (float)acc[3][1] + o1.w;
  bool valid = fg < 5;  // feats 0..39
  float m01 = v0 > v1 ? v0 : v1, m23 = v2 > v3 ? v2 : v3;
  float m45 = v4 > v5 ? v4 : v5, m67 = v6 > v7 ? v6 : v7;
  float ml = m01 > m23 ? m01 : m23;
  float mh = m45 > m67 ? m45 : m67;
  float mv = ml > mh ? ml : mh;
  mv = valid ? mv : -1e30f;
#pragma unroll
  for (int o = 1; o <= 4; o <<= 1) {
    float t = __shfl_xor(mv, o, 64);
    mv = mv > t ? mv : t;
  }
  float se = 0.f;
  if (valid)
    se = __expf(v0 - mv) + __expf(v1 - mv) + __expf(v2 - mv) + __expf(v3 - mv) +
         __expf(v4 - mv) + __expf(v5 - mv) + __expf(v6 - mv) + __expf(v7 - mv);
#pragma unroll
  for (int o = 1; o <= 4; o <<= 1) se += __shfl_xor(se, o, 64);
  if (eg == 0 && valid) {
    float ls = mv + __logf(se);
    float4 r0 = make_float4(v0 - ls, v1 - ls, v2 - ls, v3 - ls);
    float4 r1 = make_float4(v4 - ls, v5 - ls, v6 - ls, v7 - ls);
    float4* wp = (float4*)(out + (size_t)node * 40 + fg * 8);
    wp[0] = r0;
    wp[1] = r1;
  }
}

extern "C" void kernel_launch(void* const* d_in, const int* in_sizes, int n_in,
                              void* d_out, int out_size, void* d_ws, size_t ws_size,
                              hipStream_t stream) {
  const float* x = (const float*)d_in[0];
  const int* esrc = (const int*)d_in[1];
  const int* edst = (const int*)d_in[2];
  const float* eval = (const float*)d_in[3];
  const float* W1 = (const float*)d_in[4];
  const float* b1 = (const float*)d_in[5];
  const float* Wr1 = (const float*)d_in[6];
  const float* br1 = (const float*)d_in[7];
  const float* W2 = (const float*)d_in[8];
  const float* b2 = (const float*)d_in[9];
  const float* Wr2 = (const float*)d_in[10];
  const float* br2 = (const float*)d_in[11];
  float* out = (float*)d_out;

  char* ws = (char*)d_ws;
  uint16_t* xb   = (uint16_t*)(ws);              // 51,200,000
  _Float16* S1h  = (_Float16*)(ws + 51200000);   // 12,800,000
  uint16_t* h    = (uint16_t*)(ws + 64000000);   // 25,600,000
  uint16_t* WT1  = (uint16_t*)(ws + 89600000);   //    262,144
  uint16_t* WT2  = (uint16_t*)(ws + 89862144);   //     65,536
  _Float16* S2h  = (_Float16*)(ws + 89927680);   //  6,400,000 (64-padded)
  float*    oacc = (float*)(ws + 96327680);      // 12,800,000 (64-padded)
  int*      offs = (int*)(ws + 109127680);       //    200,016 (padded)
  int2*     es   = (int2*)(ws + 109327696);      //  6,400,000
  int2*     esc  = (int2*)(ws + 115727696);      //  6,400,000
  int*      bc   = (int*)(ws + 122127696);       //  2,450,000 ([block][bucket])
  int*      bc2  = (int*)(ws + 124577696);       //  2,450,000 ([bucket][block])
  int*      bucketTotal = (int*)(ws + 127027696);//        784  (total ~127 MB)

  k_pre2<<<16265, 256, 0, stream>>>(x, xb, W1, Wr1, W2, Wr2, WT1, WT2, edst, bc);
  k_p2<<<NBUCK, 256, 0, stream>>>(bc, bc2, bucketTotal);
  k_p4<<<NBLK, 256, 0, stream>>>(esrc, edst, eval, bc2, bucketTotal, esc);
  k_p5<<<NBUCK, 256, 0, stream>>>(esc, bucketTotal, es, offs);

  dim3 g1(391, 2);
  k_gemm1<<<g1, 256, 0, stream>>>(xb, WT1, N_NODES, S1h, h, br1);

  k_spmm1_csr<<<(N_NODES + 3) / 4, 256, 0, stream>>>(offs, es, S1h, b1, h);

  k_gemm2<<<391, 256, 0, stream>>>(h, WT2, N_NODES, S2h, oacc, b2, br2);

  k_spmm2_lsm<<<(N_NODES + 3) / 4, 256, 0, stream>>>(offs, es, S2h, oacc, out);
}